// Round 1
// baseline (2034.600 us; speedup 1.0000x reference)
//
#include <hip/hip_runtime.h>

// LSTM: B=2048, T=512, I=1, H=64, L=2, O=1. All fp32.
// Fused 2-layer persistent kernel:
//   - 512 blocks x 256 threads, BT=4 batch elements per block (2 blocks/CU).
//   - thread t owns gate-row t of Whh0 (64 regs) and of [Wih1|Whh1] (128 regs).
//   - h1/h2 state in LDS (broadcast reads), c-state in registers.
//   - 4 barriers per timestep: L1 matvec | L1 combine | L2 matvec | L2 combine.

#define TT 512
#define HH 64
#define BT 4   // batch per block

__device__ __forceinline__ float sigm(float x) {
    return __builtin_amdgcn_rcpf(1.f + __expf(-x));
}
__device__ __forceinline__ float tanh_f(float x) {
    float xc = fminf(fmaxf(x, -15.f), 15.f);
    float e = __expf(2.f * xc);
    return (e - 1.f) * __builtin_amdgcn_rcpf(e + 1.f);
}
__device__ __forceinline__ float dot4(float4 a, float4 b, float acc) {
    acc = fmaf(a.x, b.x, acc);
    acc = fmaf(a.y, b.y, acc);
    acc = fmaf(a.z, b.z, acc);
    acc = fmaf(a.w, b.w, acc);
    return acc;
}

__global__ __launch_bounds__(256, 2) void lstm_fused(
    const float* __restrict__ x,
    const float* __restrict__ Wih0, const float* __restrict__ Whh0,
    const float* __restrict__ bih0, const float* __restrict__ bhh0,
    const float* __restrict__ Wih1, const float* __restrict__ Whh1,
    const float* __restrict__ bih1, const float* __restrict__ bhh1,
    const float* __restrict__ fcW, const float* __restrict__ fcb,
    float* __restrict__ out)
{
    __shared__ float4 xs4[BT * TT / 4];   // x tile: 4 rows x 512, 8KB
    __shared__ float4 hc4[BT][32];        // per b: [h1(64) | h2(64)], 2KB
    __shared__ float  p[BT][256];         // gate preacts, 4KB
    __shared__ float  fcw_s[HH];

    const int t  = threadIdx.x;
    const int b0 = blockIdx.x * BT;

    // ---- stage x tile (coalesced float4) ----
    {
        const float4* xg = (const float4*)(x + (size_t)b0 * TT);
        #pragma unroll
        for (int i = 0; i < BT * TT / 4 / 256; ++i)
            xs4[t + i * 256] = xg[t + i * 256];
    }

    // ---- persistent per-thread weights (row t of each matrix) ----
    float4 w1[16], w2i[16], w2h[16];
    {
        const float4* r1 = (const float4*)(Whh0 + t * HH);
        const float4* ri = (const float4*)(Wih1 + t * HH);
        const float4* rh = (const float4*)(Whh1 + t * HH);
        #pragma unroll
        for (int k = 0; k < 16; ++k) { w1[k] = r1[k]; w2i[k] = ri[k]; w2h[k] = rh[k]; }
    }
    const float wx    = Wih0[t];
    const float bias1 = bih0[t] + bhh0[t];
    const float bias2 = bih1[t] + bhh1[t];
    if (t < HH) fcw_s[t] = fcW[t];

    // ---- zero h state ----
    {
        float4 z = make_float4(0.f, 0.f, 0.f, 0.f);
        float4* hcl = (float4*)hc4;
        if (t < BT * 32) hcl[t] = z;
    }
    float c1 = 0.f, c2 = 0.f;
    const int jb = t >> 6;   // this thread's (b, j) pair for gate combine
    const int jj = t & 63;
    float* hcf = (float*)hc4;
    const float* xsf = (const float*)xs4;

    __syncthreads();

    for (int step = 0; step < TT; ++step) {
        // ---- layer-1 matvec: p[b][t] = bias1 + wx*x[b,step] + Whh0[t,:]·h1[b] ----
        #pragma unroll
        for (int b = 0; b < BT; ++b) {
            float a0 = 0.f, a1 = 0.f, a2 = 0.f, a3 = 0.f;
            #pragma unroll
            for (int kc = 0; kc < 16; kc += 4) {
                a0 = dot4(w1[kc + 0], hc4[b][kc + 0], a0);
                a1 = dot4(w1[kc + 1], hc4[b][kc + 1], a1);
                a2 = dot4(w1[kc + 2], hc4[b][kc + 2], a2);
                a3 = dot4(w1[kc + 3], hc4[b][kc + 3], a3);
            }
            p[b][t] = ((a0 + a1) + (a2 + a3)) + fmaf(wx, xsf[b * TT + step], bias1);
        }
        __syncthreads();

        // ---- layer-1 gate combine for pair (jb, jj) ----
        {
            float gi = sigm(p[jb][jj]);
            float gf = sigm(p[jb][64 + jj]);
            float gg = tanh_f(p[jb][128 + jj]);
            float go = sigm(p[jb][192 + jj]);
            c1 = fmaf(gf, c1, gi * gg);
            hcf[jb * 128 + jj] = go * tanh_f(c1);
        }
        __syncthreads();

        // ---- layer-2 matvec: p[b][t] = bias2 + Wih1[t,:]·h1[b] + Whh1[t,:]·h2[b] ----
        #pragma unroll
        for (int b = 0; b < BT; ++b) {
            float a0 = 0.f, a1 = 0.f, a2 = 0.f, a3 = 0.f;
            #pragma unroll
            for (int kc = 0; kc < 16; kc += 4) {
                a0 = dot4(w2i[kc + 0], hc4[b][kc + 0], a0);
                a1 = dot4(w2i[kc + 1], hc4[b][kc + 1], a1);
                a2 = dot4(w2i[kc + 2], hc4[b][kc + 2], a2);
                a3 = dot4(w2i[kc + 3], hc4[b][kc + 3], a3);
            }
            #pragma unroll
            for (int kc = 0; kc < 16; kc += 4) {
                a0 = dot4(w2h[kc + 0], hc4[b][16 + kc + 0], a0);
                a1 = dot4(w2h[kc + 1], hc4[b][16 + kc + 1], a1);
                a2 = dot4(w2h[kc + 2], hc4[b][16 + kc + 2], a2);
                a3 = dot4(w2h[kc + 3], hc4[b][16 + kc + 3], a3);
            }
            p[b][t] = ((a0 + a1) + (a2 + a3)) + bias2;
        }
        __syncthreads();

        // ---- layer-2 gate combine ----
        {
            float gi = sigm(p[jb][jj]);
            float gf = sigm(p[jb][64 + jj]);
            float gg = tanh_f(p[jb][128 + jj]);
            float go = sigm(p[jb][192 + jj]);
            c2 = fmaf(gf, c2, gi * gg);
            hcf[jb * 128 + 64 + jj] = go * tanh_f(c2);
        }
        __syncthreads();
    }

    // ---- final FC: out[b] = fcW · h2_final[b] + fcb ----
    if (t < BT) {
        float s = fcb[0];
        #pragma unroll
        for (int j = 0; j < HH; ++j)
            s = fmaf(hcf[t * 128 + 64 + j], fcw_s[j], s);
        out[b0 + t] = s;
    }
}

extern "C" void kernel_launch(void* const* d_in, const int* in_sizes, int n_in,
                              void* d_out, int out_size, void* d_ws, size_t ws_size,
                              hipStream_t stream) {
    const float* x    = (const float*)d_in[0];
    const float* Wih0 = (const float*)d_in[1];
    const float* Whh0 = (const float*)d_in[2];
    const float* bih0 = (const float*)d_in[3];
    const float* bhh0 = (const float*)d_in[4];
    const float* Wih1 = (const float*)d_in[5];
    const float* Whh1 = (const float*)d_in[6];
    const float* bih1 = (const float*)d_in[7];
    const float* bhh1 = (const float*)d_in[8];
    const float* fcW  = (const float*)d_in[9];
    const float* fcb  = (const float*)d_in[10];
    float* out = (float*)d_out;

    lstm_fused<<<dim3(2048 / BT), dim3(256), 0, stream>>>(
        x, Wih0, Whh0, bih0, bhh0, Wih1, Whh1, bih1, bhh1, fcW, fcb, out);
}